// Round 5
// baseline (77.550 us; speedup 1.0000x reference)
//
#include <hip/hip_runtime.h>

// SIR recurrence, steps=200000, output = trajectory [steps-1, 3] float32.
//
// R4 -> R5: single fused dispatch. The scan converges (analytically bounded
// future change < 1e-4, threshold 4.5e-2) in ~250 steps ~= 1 us of dependent
// FP chain -- cheap enough to replay REDUNDANTLY in every block:
//   - lane 0 of each block runs the identical deterministic scan in
//     registers up to min(block_end, t_conv), storing only trajectory rows
//     inside the block's 256-row slice;
//   - broadcasts (t_cut, frozen S,I,R) via LDS;
//   - all 256 threads coalesced-fill the frozen tail of the slice.
// Deletes the 2nd dispatch and the FixInfo global round-trip (both pure
// launch-latency). Termination: division-free analytic stop
//   I*max(g, b*S) < 1e-4 * (1-f)      [valid bound for any 1-f > 0]
// plus bitwise one-step fixpoint backstop (hard cap ~1100 steps, R1
// evidence: I underflows to 0 => exact fixpoint).

#define ROWS_PER_BLOCK 256

__global__ __launch_bounds__(256) void sir_fused(
        const float* __restrict__ x,
        const float* __restrict__ bw,
        const float* __restrict__ gw,
        float* __restrict__ out, int n) {
    __shared__ float fS, fI, fR;
    __shared__ int   tcut;   // first row of slice to fill with frozen state

    const int r0 = blockIdx.x * ROWS_PER_BLOCK;
    const int r1 = min(r0 + ROWS_PER_BLOCK, n);

    if (threadIdx.x == 0) {
        float S = x[0], I = x[1], R = x[2];
        float b = bw[0], g = gw[0];
        float cg = 1.0f - g;
        int t = 0;
        int cut = r1;                    // default: scan covered whole slice
        while (t < r1) {
            float f  = fmaf(b, S, cg);   // 1 + b*S - g
            float t1 = b * I;
            float nS = fmaf(-t1, S, S);  // S - b*S*I
            float nI = I * f;            // I*(1 + b*S - g)
            float nR = fmaf(g, I, R);    // R + g*I
            bool bitfix = (nS == S) && (nI == I) && (nR == R);
            S = nS; I = nI; R = nR;
            if (t >= r0) {
                out[3 * t + 0] = S;
                out[3 * t + 1] = I;
                out[3 * t + 2] = R;
            }
            ++t;
            // analytic stop, division-free:
            //   rem = I/(1-f') bounds future I-sum; change < rem*max(g,b*S)
            float f2  = fmaf(b, S, cg);
            float omf = 1.0f - f2;       // = g - b*S
            float bS  = f2 - cg;         // = b*S
            if (bitfix || (I * fmaxf(g, bS) < 1e-4f * omf)) { cut = t; break; }
        }
        fS = S; fI = I; fR = R;
        tcut = max(cut, r0);
    }
    __syncthreads();

    const int cut = tcut;
    if (cut >= r1) return;               // slice fully written by scan
    const float s = fS, i = fI, r = fR;
    const int e0 = 3 * r0;
    const int e1 = 3 * r1;
    const int ec = 3 * cut;
#pragma unroll
    for (int k = 0; k < 3; ++k) {
        int e = e0 + (int)threadIdx.x + k * 256;
        if (e < e1 && e >= ec) {
            int c = e - 3 * (e / 3);
            out[e] = (c == 0) ? s : (c == 1) ? i : r;
        }
    }
}

extern "C" void kernel_launch(void* const* d_in, const int* in_sizes, int n_in,
                              void* d_out, int out_size, void* d_ws, size_t ws_size,
                              hipStream_t stream) {
    const float* x  = (const float*)d_in[0];
    const float* bw = (const float*)d_in[1];
    const float* gw = (const float*)d_in[2];
    float* out = (float*)d_out;
    int n = out_size / 3;  // steps - 1 rows

    int blocks = (n + ROWS_PER_BLOCK - 1) / ROWS_PER_BLOCK;
    sir_fused<<<blocks, 256, 0, stream>>>(x, bw, gw, out, n);
}

// Round 6
// 67.106 us; speedup vs baseline: 1.1556x; 1.1556x over previous
//
#include <hip/hip_runtime.h>

// SIR recurrence, steps=200000, output = trajectory [steps-1, 3] float32.
//
// R5 -> R6: revert to R4's two-dispatch structure (fusion regressed:
// 66.4 -> 77.5 us; redundant per-block scans with per-iteration exit
// branches cost more than the saved launch latency). Single delta vs R4:
// octet stores packed into 6 global_store_dwordx4 built from NAMED scalar
// registers (no float[24] punning -- that was R3's miscompile). Math is
// bit-identical to R4; analytic stop fires at the same step.

struct FixInfo {
    int   t;        // first row index NOT written by the scan kernel
    float S, I, R;  // state to replicate into rows [t, n)
};

__global__ void sir_scan(const float* __restrict__ x,
                         const float* __restrict__ bw,
                         const float* __restrict__ gw,
                         float* __restrict__ out,
                         int n, FixInfo* __restrict__ fi) {
    if (threadIdx.x != 0) return;
    float S = x[0], I = x[1], R = x[2];
    float b = bw[0], g = gw[0];
    float cg = 1.0f - g;

    int t = 0;
    bool fixed = false;
    float* p = out;

    // main loop: octets of 8 steps; stores packed; checks once per octet
    while (t + 8 <= n) {
        float pS = S, pI = I, pR = R;     // state one step before octet end
        float v0, v1, v2, v3, v4, v5, v6, v7, v8, v9, v10, v11,
              v12, v13, v14, v15, v16, v17, v18, v19, v20, v21, v22, v23;
#pragma unroll
        for (int k = 0; k < 8; ++k) {
            pS = S; pI = I; pR = R;
            float f  = fmaf(b, S, cg);    // 1 + b*S - g
            float t1 = b * I;
            float nS = fmaf(-t1, S, S);   // S - b*S*I
            float nI = I * f;             // I*(1 + b*S - g)
            float nR = fmaf(g, I, R);     // R + g*I
            S = nS; I = nI; R = nR;
            switch (k) {
                case 0: v0  = S; v1  = I; v2  = R; break;
                case 1: v3  = S; v4  = I; v5  = R; break;
                case 2: v6  = S; v7  = I; v8  = R; break;
                case 3: v9  = S; v10 = I; v11 = R; break;
                case 4: v12 = S; v13 = I; v14 = R; break;
                case 5: v15 = S; v16 = I; v17 = R; break;
                case 6: v18 = S; v19 = I; v20 = R; break;
                case 7: v21 = S; v22 = I; v23 = R; break;
            }
        }
        float4* o4 = reinterpret_cast<float4*>(p);  // p is 16B-aligned:
        o4[0] = make_float4(v0,  v1,  v2,  v3);     // out 256B-aligned, +96B/octet
        o4[1] = make_float4(v4,  v5,  v6,  v7);
        o4[2] = make_float4(v8,  v9,  v10, v11);
        o4[3] = make_float4(v12, v13, v14, v15);
        o4[4] = make_float4(v16, v17, v18, v19);
        o4[5] = make_float4(v20, v21, v22, v23);
        p += 24;
        t += 8;

        // backstop: exact bitwise one-step fixpoint
        if (S == pS && I == pI && R == pR) { fixed = true; break; }

        // analytic early stop: bounded total future change < 1e-4
        float f_next = fmaf(b, S, cg);
        if (f_next < 0.99999f) {
            float rem = I / (1.0f - f_next);        // >= sum of future I
            if (rem * fmaxf(g, b * S) < 1e-4f) { fixed = true; break; }
        }
    }

    // tail (only if we never stopped early): run honestly to n
    if (!fixed) {
        while (t < n) {
            float f  = fmaf(b, S, cg);
            float t1 = b * I;
            float nS = fmaf(-t1, S, S);
            float nI = I * f;
            float nR = fmaf(g, I, R);
            S = nS; I = nI; R = nR;
            p[0] = S; p[1] = I; p[2] = R;
            p += 3;
            ++t;
        }
    }

    fi->t = t; fi->S = S; fi->I = I; fi->R = R;
}

// One float element per thread; elements >= 3*t0 get the frozen state.
__global__ void sir_fill(float* __restrict__ out, int total,
                         const FixInfo* __restrict__ fi) {
    int j = blockIdx.x * blockDim.x + threadIdx.x;
    if (j >= total) return;
    int j0 = 3 * fi->t;
    if (j < j0) return;
    int c = j % 3;
    float v = (c == 0) ? fi->S : (c == 1) ? fi->I : fi->R;
    out[j] = v;
}

extern "C" void kernel_launch(void* const* d_in, const int* in_sizes, int n_in,
                              void* d_out, int out_size, void* d_ws, size_t ws_size,
                              hipStream_t stream) {
    const float* x  = (const float*)d_in[0];
    const float* bw = (const float*)d_in[1];
    const float* gw = (const float*)d_in[2];
    float* out = (float*)d_out;
    int n = out_size / 3;  // steps - 1 rows

    FixInfo* fi = (FixInfo*)d_ws;

    sir_scan<<<1, 64, 0, stream>>>(x, bw, gw, out, n, fi);

    int blocks = (out_size + 255) / 256;
    sir_fill<<<blocks, 256, 0, stream>>>(out, out_size, fi);
}